// Round 7
// baseline (321.139 us; speedup 1.0000x reference)
//
#include <hip/hip_runtime.h>
#include <math.h>

// Problem constants: B=2, S=2048, D=1024, H=16, DC=16, DH=64
typedef short short8 __attribute__((ext_vector_type(8)));
typedef short short4t __attribute__((ext_vector_type(4)));
typedef float f32x4  __attribute__((ext_vector_type(4)));

__device__ __forceinline__ unsigned cvt_pk_bf16(float lo, float hi) {
    unsigned r;
    asm("v_cvt_pk_bf16_f32 %0, %1, %2" : "=v"(r) : "v"(lo), "v"(hi));
    return r;
}
__device__ __forceinline__ unsigned f2bf_rne(float x) {
    unsigned u = __float_as_uint(x);
    return (u + 0x7fffu + ((u >> 16) & 1u)) >> 16;
}
__device__ __forceinline__ float exp2_fast(float x) {   // v_exp_f32 computes 2^x
    float r;
    asm("v_exp_f32 %0, %1" : "=v"(r) : "v"(x));
    return r;
}
// 16x16x16 bf16 MFMA (K=16): B-frag layout matches the 16x16 D-layout of the
// score MFMA, so P needs NO cross-lane redistribution before PV.
__device__ __forceinline__ f32x4 mfma_k16(short4t a, short4t b, f32x4 c) {
#if __has_builtin(__builtin_amdgcn_mfma_f32_16x16x16bf16_1k)
    return __builtin_amdgcn_mfma_f32_16x16x16bf16_1k(a, b, c, 0, 0, 0);
#else
    asm volatile("v_mfma_f32_16x16x16_bf16 %0, %1, %2, %0" : "+v"(c) : "v"(a), "v"(b));
    return c;
#endif
}

// ---------------------------------------------------------------------------
// fp32 -> bf16 bulk convert (8 elems/thread)
// ---------------------------------------------------------------------------
__global__ __launch_bounds__(256) void f2bf_kernel(const float* __restrict__ in,
                                                   short* __restrict__ out, int n8) {
    const int i = blockIdx.x * 256 + threadIdx.x;
    if (i >= n8) return;
    const float4 a = ((const float4*)in)[2 * i];
    const float4 b = ((const float4*)in)[2 * i + 1];
    uint4 r;
    r.x = cvt_pk_bf16(a.x, a.y);
    r.y = cvt_pk_bf16(a.z, a.w);
    r.z = cvt_pk_bf16(b.x, b.y);
    r.w = cvt_pk_bf16(b.z, b.w);
    ((uint4*)out)[i] = r;
}

// Wv, Wo, Wn weight converts in one launch (grid 1032)
__global__ __launch_bounds__(256) void f2bfW(const float* __restrict__ Wv,
                                             const float* __restrict__ Wo,
                                             const float* __restrict__ Wn,
                                             short* __restrict__ Wvb,
                                             short* __restrict__ Wob,
                                             short* __restrict__ Wnb) {
    const int i = blockIdx.x * 256 + threadIdx.x;
    const float* src;
    short* dst;
    int ii;
    if (i < 131072)      { src = Wv; dst = Wvb; ii = i; }
    else if (i < 262144) { src = Wo; dst = Wob; ii = i - 131072; }
    else                 { src = Wn; dst = Wnb; ii = i - 262144; }
    const float4 a = ((const float4*)src)[2 * ii];
    const float4 b = ((const float4*)src)[2 * ii + 1];
    uint4 r;
    r.x = cvt_pk_bf16(a.x, a.y);
    r.y = cvt_pk_bf16(a.z, a.w);
    r.z = cvt_pk_bf16(b.x, b.y);
    r.w = cvt_pk_bf16(b.z, b.w);
    ((uint4*)dst)[ii] = r;
}

// ---------------------------------------------------------------------------
// z = coords @ Wc.T + bc, per head h with ch = -softplus(gamma_h)*log2(e):
//   ZA[b,h,s,32] = [z(16), zsq, 1, 0...]          (keys / A-operand)
//   ZB[b,h,s,32] = [-2*ch*z(16), ch, ch*zsq, 0..] (queries / B-operand)
// => MFMA(ZA_k, ZB_q) = ch * (zsq_k + zsq_q - 2 z_k.z_q) = exp2 argument.
// ---------------------------------------------------------------------------
__global__ __launch_bounds__(256) void zker3(const float* __restrict__ coords,
                                             const float* __restrict__ Wc,
                                             const float* __restrict__ bc,
                                             const float* __restrict__ gamma,
                                             short* __restrict__ ZA,
                                             short* __restrict__ ZB) {
    const int bs = blockIdx.x;
    const int b = bs >> 11, s = bs & 2047;
    const int tid = threadIdx.x;
    __shared__ float csh[16];
    if (tid < 16) csh[tid] = coords[(size_t)bs * 16 + tid];
    __syncthreads();
    float z = bc[tid];
#pragma unroll
    for (int k = 0; k < 16; k++) z = fmaf(csh[k], Wc[tid * 16 + k], z);
    const unsigned ub = f2bf_rne(z);
    const float zb = __uint_as_float(ub << 16);
    float sq = zb * zb;
    sq += __shfl_xor(sq, 1, 64);
    sq += __shfl_xor(sq, 2, 64);
    sq += __shfl_xor(sq, 4, 64);
    sq += __shfl_xor(sq, 8, 64);
    const int h = tid >> 4, c = tid & 15;
    const float gm = gamma[h];
    const float sp = fmaxf(gm, 0.f) + log1pf(__expf(-fabsf(gm)));  // softplus
    const float ch = -sp * 1.4426950408889634f;                    // -g*log2(e)
    const size_t row = ((size_t)(b * 16 + h) * 2048 + s) * 32;
    ZA[row + c] = (short)ub;
    ZA[row + 16 + c] = (c == 0) ? (short)f2bf_rne(sq)
                                : (c == 1 ? (short)0x3F80 : (short)0);
    ZB[row + c] = (short)f2bf_rne(-2.f * ch * zb);
    ZB[row + 16 + c] = (c == 0) ? (short)f2bf_rne(ch)
                                : (c == 1 ? (short)f2bf_rne(ch * sq) : (short)0);
}

// ---------------------------------------------------------------------------
// bf16 MFMA GEMM: C[m,n] = sum_k A[m,k]*W[n,k] + bias[n].  M=4096,N=1024,K=1024
// 128x64 tile, BK=32, 4 waves (2x2 of 64x32), double-buffered LDS via
// global_load_lds w16; chunk-XOR swizzle via pre-swizzled global source.
// EPI=0: write V^T bf16 [b,h,dh,s];  EPI=1: fp32 row-major [m,n]
// ---------------------------------------------------------------------------
template <int EPI>
__global__ __launch_bounds__(256) void gemm_mfma(const short* __restrict__ A,
                                                 const short* __restrict__ W,
                                                 const float* __restrict__ bias,
                                                 void* __restrict__ Cout) {
    __shared__ short As[2][128][32];
    __shared__ short Bs[2][64][32];
    const int tid = threadIdx.x;
    const int wv = tid >> 6, l = tid & 63, g = l >> 4, qc = l & 15;
    const int wm = wv >> 1, wn = wv & 1;
    const int Mb = blockIdx.y * 128, Nb = blockIdx.x * 64;

    auto stage = [&](int buf, int k0) {
        const short* ga = A + (size_t)Mb * 1024 + k0;
        const short* gb = W + (size_t)Nb * 1024 + k0;
#pragma unroll
        for (int i = 0; i < 2; i++) {
            const int c = i * 256 + tid;                 // A chunk id 0..511
            const int r = c >> 2, jp = c & 3;
            const int js = jp ^ ((r >> 1) & 3);          // pre-swizzled source
            const short* gsA = ga + (size_t)r * 1024 + js * 8;
            short* ldsA = &As[buf][0][0] + (size_t)(i * 256 + wv * 64) * 8;
            __builtin_amdgcn_global_load_lds((const __attribute__((address_space(1))) void*)gsA,
                                             (__attribute__((address_space(3))) void*)ldsA, 16, 0, 0);
        }
        {
            const int r = tid >> 2, jp = tid & 3;
            const int js = jp ^ ((r >> 1) & 3);
            const short* gsB = gb + (size_t)r * 1024 + js * 8;
            short* ldsB = &Bs[buf][0][0] + (size_t)(wv * 64) * 8;
            __builtin_amdgcn_global_load_lds((const __attribute__((address_space(1))) void*)gsB,
                                             (__attribute__((address_space(3))) void*)ldsB, 16, 0, 0);
        }
    };

    const int csw = (g ^ ((qc >> 1) & 3)) * 8;   // swizzled read chunk offset

    f32x4 acc[4][2] = {};
    stage(0, 0);
    __syncthreads();
    int cur = 0;
#pragma unroll 1
    for (int kb = 0; kb < 32; kb++) {
        if (kb < 31) stage(cur ^ 1, (kb + 1) * 32);
        short8 af[4], bfr[2];
#pragma unroll
        for (int mt = 0; mt < 4; mt++)
            af[mt] = *(const short8*)&As[cur][wm * 64 + mt * 16 + qc][csw];
#pragma unroll
        for (int nt = 0; nt < 2; nt++)
            bfr[nt] = *(const short8*)&Bs[cur][wn * 32 + nt * 16 + qc][csw];
#pragma unroll
        for (int mt = 0; mt < 4; mt++)
#pragma unroll
            for (int nt = 0; nt < 2; nt++)
                acc[mt][nt] = __builtin_amdgcn_mfma_f32_16x16x32_bf16(af[mt], bfr[nt], acc[mt][nt], 0, 0, 0);
        __syncthreads();
        cur ^= 1;
    }

    float bl[2];
#pragma unroll
    for (int nt = 0; nt < 2; nt++) bl[nt] = bias[Nb + wn * 32 + nt * 16 + qc];
#pragma unroll
    for (int mt = 0; mt < 4; mt++) {
#pragma unroll
        for (int nt = 0; nt < 2; nt++) {
            const int m0 = Mb + wm * 64 + mt * 16 + g * 4;
            const int n  = Nb + wn * 32 + nt * 16 + qc;
            f32x4 v = acc[mt][nt];
            v = v + bl[nt];
            if (EPI == 0) {
                const int bb = m0 >> 11, s0 = m0 & 2047;
                const int hh = n >> 6, dh = n & 63;
                uint2 p2;
                p2.x = cvt_pk_bf16(v[0], v[1]);
                p2.y = cvt_pk_bf16(v[2], v[3]);
                *(uint2*)((short*)Cout + (size_t)((bb * 16 + hh) * 64 + dh) * 2048 + s0) = p2;
            } else {
                float* C = (float*)Cout;
#pragma unroll
                for (int i = 0; i < 4; i++) C[(size_t)(m0 + i) * 1024 + n] = v[i];
            }
        }
    }
}

// ---------------------------------------------------------------------------
// Fused MFMA flash attention (v5): NO LDS, no barriers — V/Z are L2-resident,
// fragments loaded directly from global (zk loads are 1KB-contiguous per
// instruction; vf kt-chunks jointly cover full cache lines, L1-reused by the
// block's 4 waves).  16 queries/wave, 64 q/block, fully independent waves.
// Bijective XCD swizzle keeps each XCD's working set to 4 (b,h) panels.
// ---------------------------------------------------------------------------
__global__ __launch_bounds__(256, 4) void attn_mfma5(const short* __restrict__ ZAg,
                                                     const short* __restrict__ ZBg,
                                                     const short* __restrict__ Vt,
                                                     short* __restrict__ AOb) {
    const int tid = threadIdx.x;
    const int wv = tid >> 6, l = tid & 63, g = l >> 4, qc = l & 15;
    // XCD-aware bijective swizzle of 1024 blocks (1024 % 8 == 0)
    const int lin = blockIdx.x;
    const int work = (lin & 7) * 128 + (lin >> 3);
    const int qb = work & 31, h = (work >> 5) & 15, b = work >> 9;
    const int bh = b * 16 + h;
    const int q0 = qb * 64 + wv * 16;

    const short* ZAb = ZAg + (size_t)bh * (2048 * 32);
    const short* ZBb = ZBg + (size_t)bh * (2048 * 32);
    const short* Vb  = Vt  + (size_t)bh * (64 * 2048);

    const short8 zq = *(const short8*)(ZBb + (size_t)(q0 + qc) * 32 + g * 8);

    union { unsigned u[2]; short4t s4; } ones4;
    ones4.u[0] = ones4.u[1] = (qc == 0) ? 0x3F803F80u : 0u;  // A row 0 = ones

    f32x4 acc[4] = {};
    f32x4 accl = {};

    const short* zrow = ZAb + (size_t)qc * 32 + g * 8;          // + (kb+kt*16)*32
    const short* vrow = Vb + (size_t)qc * 2048 + g * 4;         // + mt*16*2048 + kb + kt*16

#pragma unroll 1
    for (int kb = 0; kb < 2048; kb += 64) {
        // scores
        short8 zk[4];
#pragma unroll
        for (int kt = 0; kt < 4; kt++)
            zk[kt] = *(const short8*)(zrow + (size_t)(kb + kt * 16) * 32);

        const f32x4 z4 = {0.f, 0.f, 0.f, 0.f};
        f32x4 S[4];
        __builtin_amdgcn_s_setprio(1);
#pragma unroll
        for (int kt = 0; kt < 4; kt++)
            S[kt] = __builtin_amdgcn_mfma_f32_16x16x32_bf16(zk[kt], zq, z4, 0, 0, 0);
        __builtin_amdgcn_s_setprio(0);

        // first half of V fragments in flight while exp2 runs
        short4t vf0[2][4];
#pragma unroll
        for (int kt = 0; kt < 2; kt++)
#pragma unroll
            for (int mt = 0; mt < 4; mt++)
                vf0[kt][mt] = *(const short4t*)(vrow + (size_t)(mt * 16) * 2048 + kb + kt * 16);

        // p = exp2(min(S,0)); pack -> per-kt B-fragment (D-layout == B-frag)
        unsigned pk[4][2];
#pragma unroll
        for (int kt = 0; kt < 4; kt++) {
            const float p0 = exp2_fast(fminf(S[kt][0], 0.f));
            const float p1 = exp2_fast(fminf(S[kt][1], 0.f));
            const float p2 = exp2_fast(fminf(S[kt][2], 0.f));
            const float p3 = exp2_fast(fminf(S[kt][3], 0.f));
            pk[kt][0] = cvt_pk_bf16(p0, p1);
            pk[kt][1] = cvt_pk_bf16(p2, p3);
        }

        // second half of V fragments
        short4t vf1[2][4];
#pragma unroll
        for (int kt = 0; kt < 2; kt++)
#pragma unroll
            for (int mt = 0; mt < 4; mt++)
                vf1[kt][mt] = *(const short4t*)(vrow + (size_t)(mt * 16) * 2048 + kb + (kt + 2) * 16);

        // PV + l via K=16 MFMAs (B = packed P directly)
        __builtin_amdgcn_s_setprio(1);
#pragma unroll
        for (int kt = 0; kt < 4; kt++) {
            union { unsigned u[2]; short4t s4; } pb;
            pb.u[0] = pk[kt][0];
            pb.u[1] = pk[kt][1];
            accl = mfma_k16(ones4.s4, pb.s4, accl);
#pragma unroll
            for (int mt = 0; mt < 4; mt++) {
                const short4t a = (kt < 2) ? vf0[kt][mt] : vf1[kt - 2][mt];
                acc[mt] = mfma_k16(a, pb.s4, acc[mt]);
            }
        }
        __builtin_amdgcn_s_setprio(0);
    }

    // epilogue: l sits at D(row0,col qc) = lane qc, reg 0
    const float lv = __shfl(accl[0], qc, 64);
    const float inv = 1.f / lv;
    const size_t row = (size_t)(b * 2048 + q0 + qc) * 1024 + h * 64;
#pragma unroll
    for (int mt = 0; mt < 4; mt++) {
        uint2 o;
        o.x = cvt_pk_bf16(acc[mt][0] * inv, acc[mt][1] * inv);
        o.y = cvt_pk_bf16(acc[mt][2] * inv, acc[mt][3] * inv);
        *(uint2*)(AOb + row + mt * 16 + g * 4) = o;
    }
}

// ---------------------------------------------------------------------------
// updated_coords = hsb(bf16) @ Wnb.T + bn via MFMA.  M=4096, N=16, K=1024.
// Runs BEFORE attn overwrites hsb (AOb alias).
// ---------------------------------------------------------------------------
__global__ __launch_bounds__(256) void coords_mfma(const short* __restrict__ A,
                                                   const short* __restrict__ Wnb,
                                                   const float* __restrict__ bn,
                                                   float* __restrict__ out1) {
    __shared__ float red[4][16][16];
    const int tid = threadIdx.x;
    const int wv = tid >> 6, l = tid & 63, g = l >> 4, qc = l & 15;
    const int m0 = blockIdx.x * 16;
    const int k0 = wv * 256;
    f32x4 acc = {};
#pragma unroll
    for (int kk = 0; kk < 256; kk += 32) {
        const short8 af = *(const short8*)(A + (size_t)(m0 + qc) * 1024 + k0 + kk + g * 8);
        const short8 bf = *(const short8*)(Wnb + (size_t)qc * 1024 + k0 + kk + g * 8);
        acc = __builtin_amdgcn_mfma_f32_16x16x32_bf16(af, bf, acc, 0, 0, 0);
    }
#pragma unroll
    for (int i2 = 0; i2 < 4; i2++) red[wv][g * 4 + i2][qc] = acc[i2];
    __syncthreads();
    const int r = tid >> 4, c = tid & 15;
    const float s = red[0][r][c] + red[1][r][c] + red[2][r][c] + red[3][r][c] + bn[c];
    out1[(size_t)(m0 + r) * 16 + c] = s;
}

// ---------------------------------------------------------------------------
extern "C" void kernel_launch(void* const* d_in, const int* in_sizes, int n_in,
                              void* d_out, int out_size, void* d_ws, size_t ws_size,
                              hipStream_t stream) {
    (void)in_sizes; (void)n_in; (void)out_size; (void)ws_size;
    const float* hidden = (const float*)d_in[0];
    const float* coords = (const float*)d_in[1];
    const float* Wv = (const float*)d_in[2];
    const float* bv = (const float*)d_in[3];
    const float* Wc = (const float*)d_in[4];
    const float* bc = (const float*)d_in[5];
    const float* Wn = (const float*)d_in[6];
    const float* bn = (const float*)d_in[7];
    const float* Wo = (const float*)d_in[8];
    const float* bo = (const float*)d_in[9];
    const float* gamma = (const float*)d_in[10];

    char* wsb = (char*)d_ws;
    short* hsb = (short*)(wsb);                    // 0..8 MB  [4096,1024] bf16
    short* AOb = hsb;                              // aliases hsb (hsb dead after coords_mfma)
    short* Wvb = (short*)(wsb + (8 << 20));        // 8..10 MB
    short* Wob = (short*)(wsb + (10 << 20));       // 10..12 MB
    short* Vt  = (short*)(wsb + (12 << 20));       // 12..20 MB [b,h,dh,s] bf16
    short* ZA  = (short*)(wsb + (20 << 20));       // 20..24 MB [b,h,s,32] bf16
    short* ZB  = (short*)(wsb + (24 << 20));       // 24..28 MB [b,h,s,32] bf16
    short* Wnb = (short*)(wsb + (28 << 20));       // 28 MB + 32 KB [16,1024] bf16

    float* out_hidden = (float*)d_out;             // [B,S,D]
    float* out_coords = out_hidden + 4194304;      // [B,S,CD]

    f2bf_kernel<<<2048, 256, 0, stream>>>(hidden, hsb, 524288);
    f2bfW<<<1032, 256, 0, stream>>>(Wv, Wo, Wn, Wvb, Wob, Wnb);
    zker3<<<4096, 256, 0, stream>>>(coords, Wc, bc, gamma, ZA, ZB);
    gemm_mfma<0><<<dim3(16, 32), 256, 0, stream>>>(hsb, Wvb, bv, (void*)Vt);
    coords_mfma<<<256, 256, 0, stream>>>(hsb, Wnb, bn, out_coords);
    attn_mfma5<<<1024, 256, 0, stream>>>(ZA, ZB, Vt, AOb);
    gemm_mfma<1><<<dim3(16, 32), 256, 0, stream>>>(AOb, Wob, bo, (void*)out_hidden);
}

// Round 8
// 119.034 us; speedup vs baseline: 2.6979x; 2.6979x over previous
//
#include <hip/hip_runtime.h>
#include <math.h>

// Problem constants: B=2, S=2048, D=1024, H=16, DC=16, DH=64
typedef short short8 __attribute__((ext_vector_type(8)));
typedef short short4t __attribute__((ext_vector_type(4)));
typedef float f32x4  __attribute__((ext_vector_type(4)));

#define AS1 __attribute__((address_space(1)))
#define AS3 __attribute__((address_space(3)))

__device__ __forceinline__ unsigned cvt_pk_bf16(float lo, float hi) {
    unsigned r;
    asm("v_cvt_pk_bf16_f32 %0, %1, %2" : "=v"(r) : "v"(lo), "v"(hi));
    return r;
}
__device__ __forceinline__ unsigned f2bf_rne(float x) {
    unsigned u = __float_as_uint(x);
    return (u + 0x7fffu + ((u >> 16) & 1u)) >> 16;
}
__device__ __forceinline__ float exp2_fast(float x) {   // v_exp_f32 computes 2^x
    float r;
    asm("v_exp_f32 %0, %1" : "=v"(r) : "v"(x));
    return r;
}
// 16x16x16 bf16 MFMA (K=16): B-frag layout matches the 16x16 D-layout of the
// score MFMA, so P needs NO cross-lane redistribution before PV.
__device__ __forceinline__ f32x4 mfma_k16(short4t a, short4t b, f32x4 c) {
#if __has_builtin(__builtin_amdgcn_mfma_f32_16x16x16bf16_1k)
    return __builtin_amdgcn_mfma_f32_16x16x16bf16_1k(a, b, c, 0, 0, 0);
#else
    asm volatile("v_mfma_f32_16x16x16_bf16 %0, %1, %2, %0" : "+v"(c) : "v"(a), "v"(b));
    return c;
#endif
}

// ---------------------------------------------------------------------------
// fp32 -> bf16 bulk convert (8 elems/thread)
// ---------------------------------------------------------------------------
__global__ __launch_bounds__(256) void f2bf_kernel(const float* __restrict__ in,
                                                   short* __restrict__ out, int n8) {
    const int i = blockIdx.x * 256 + threadIdx.x;
    if (i >= n8) return;
    const float4 a = ((const float4*)in)[2 * i];
    const float4 b = ((const float4*)in)[2 * i + 1];
    uint4 r;
    r.x = cvt_pk_bf16(a.x, a.y);
    r.y = cvt_pk_bf16(a.z, a.w);
    r.z = cvt_pk_bf16(b.x, b.y);
    r.w = cvt_pk_bf16(b.z, b.w);
    ((uint4*)out)[i] = r;
}

// Wv, Wo, Wn weight converts in one launch (grid 1032)
__global__ __launch_bounds__(256) void f2bfW(const float* __restrict__ Wv,
                                             const float* __restrict__ Wo,
                                             const float* __restrict__ Wn,
                                             short* __restrict__ Wvb,
                                             short* __restrict__ Wob,
                                             short* __restrict__ Wnb) {
    const int i = blockIdx.x * 256 + threadIdx.x;
    const float* src;
    short* dst;
    int ii;
    if (i < 131072)      { src = Wv; dst = Wvb; ii = i; }
    else if (i < 262144) { src = Wo; dst = Wob; ii = i - 131072; }
    else                 { src = Wn; dst = Wnb; ii = i - 262144; }
    const float4 a = ((const float4*)src)[2 * ii];
    const float4 b = ((const float4*)src)[2 * ii + 1];
    uint4 r;
    r.x = cvt_pk_bf16(a.x, a.y);
    r.y = cvt_pk_bf16(a.z, a.w);
    r.z = cvt_pk_bf16(b.x, b.y);
    r.w = cvt_pk_bf16(b.z, b.w);
    ((uint4*)dst)[ii] = r;
}

// ---------------------------------------------------------------------------
// z = coords @ Wc.T + bc, per head h with ch = -softplus(gamma_h)*log2(e):
//   ZA[b,h,s,32] = [z(16), zsq, 1, 0...]          (keys / A-operand)
//   ZB[b,h,s,32] = [-2*ch*z(16), ch, ch*zsq, 0..] (queries / B-operand)
// => MFMA(ZA_k, ZB_q) = ch * (zsq_k + zsq_q - 2 z_k.z_q) = exp2 argument.
// ---------------------------------------------------------------------------
__global__ __launch_bounds__(256) void zker3(const float* __restrict__ coords,
                                             const float* __restrict__ Wc,
                                             const float* __restrict__ bc,
                                             const float* __restrict__ gamma,
                                             short* __restrict__ ZA,
                                             short* __restrict__ ZB) {
    const int bs = blockIdx.x;
    const int b = bs >> 11, s = bs & 2047;
    const int tid = threadIdx.x;
    __shared__ float csh[16];
    if (tid < 16) csh[tid] = coords[(size_t)bs * 16 + tid];
    __syncthreads();
    float z = bc[tid];
#pragma unroll
    for (int k = 0; k < 16; k++) z = fmaf(csh[k], Wc[tid * 16 + k], z);
    const unsigned ub = f2bf_rne(z);
    const float zb = __uint_as_float(ub << 16);
    float sq = zb * zb;
    sq += __shfl_xor(sq, 1, 64);
    sq += __shfl_xor(sq, 2, 64);
    sq += __shfl_xor(sq, 4, 64);
    sq += __shfl_xor(sq, 8, 64);
    const int h = tid >> 4, c = tid & 15;
    const float gm = gamma[h];
    const float sp = fmaxf(gm, 0.f) + log1pf(__expf(-fabsf(gm)));  // softplus
    const float ch = -sp * 1.4426950408889634f;                    // -g*log2(e)
    const size_t row = ((size_t)(b * 16 + h) * 2048 + s) * 32;
    ZA[row + c] = (short)ub;
    ZA[row + 16 + c] = (c == 0) ? (short)f2bf_rne(sq)
                                : (c == 1 ? (short)0x3F80 : (short)0);
    ZB[row + c] = (short)f2bf_rne(-2.f * ch * zb);
    ZB[row + 16 + c] = (c == 0) ? (short)f2bf_rne(ch)
                                : (c == 1 ? (short)f2bf_rne(ch * sq) : (short)0);
}

// ---------------------------------------------------------------------------
// bf16 MFMA GEMM: C[m,n] = sum_k A[m,k]*W[n,k] + bias[n].  M=4096,N=1024,K=1024
// 128x64 tile, BK=32, 4 waves (2x2 of 64x32), double-buffered LDS via
// global_load_lds w16; chunk-XOR swizzle via pre-swizzled global source.
// EPI=0: write V^T bf16 [b,h,dh,s];  EPI=1: fp32 row-major [m,n]
// ---------------------------------------------------------------------------
template <int EPI>
__global__ __launch_bounds__(256) void gemm_mfma(const short* __restrict__ A,
                                                 const short* __restrict__ W,
                                                 const float* __restrict__ bias,
                                                 void* __restrict__ Cout) {
    __shared__ short As[2][128][32];
    __shared__ short Bs[2][64][32];
    const int tid = threadIdx.x;
    const int wv = tid >> 6, l = tid & 63, g = l >> 4, qc = l & 15;
    const int wm = wv >> 1, wn = wv & 1;
    const int Mb = blockIdx.y * 128, Nb = blockIdx.x * 64;

    auto stage = [&](int buf, int k0) {
        const short* ga = A + (size_t)Mb * 1024 + k0;
        const short* gb = W + (size_t)Nb * 1024 + k0;
#pragma unroll
        for (int i = 0; i < 2; i++) {
            const int c = i * 256 + tid;                 // A chunk id 0..511
            const int r = c >> 2, jp = c & 3;
            const int js = jp ^ ((r >> 1) & 3);          // pre-swizzled source
            const short* gsA = ga + (size_t)r * 1024 + js * 8;
            short* ldsA = &As[buf][0][0] + (size_t)(i * 256 + wv * 64) * 8;
            __builtin_amdgcn_global_load_lds((const AS1 void*)gsA, (AS3 void*)ldsA, 16, 0, 0);
        }
        {
            const int r = tid >> 2, jp = tid & 3;
            const int js = jp ^ ((r >> 1) & 3);
            const short* gsB = gb + (size_t)r * 1024 + js * 8;
            short* ldsB = &Bs[buf][0][0] + (size_t)(wv * 64) * 8;
            __builtin_amdgcn_global_load_lds((const AS1 void*)gsB, (AS3 void*)ldsB, 16, 0, 0);
        }
    };

    const int csw = (g ^ ((qc >> 1) & 3)) * 8;   // swizzled read chunk offset

    f32x4 acc[4][2] = {};
    stage(0, 0);
    __syncthreads();
    int cur = 0;
#pragma unroll 1
    for (int kb = 0; kb < 32; kb++) {
        if (kb < 31) stage(cur ^ 1, (kb + 1) * 32);
        short8 af[4], bfr[2];
#pragma unroll
        for (int mt = 0; mt < 4; mt++)
            af[mt] = *(const short8*)&As[cur][wm * 64 + mt * 16 + qc][csw];
#pragma unroll
        for (int nt = 0; nt < 2; nt++)
            bfr[nt] = *(const short8*)&Bs[cur][wn * 32 + nt * 16 + qc][csw];
#pragma unroll
        for (int mt = 0; mt < 4; mt++)
#pragma unroll
            for (int nt = 0; nt < 2; nt++)
                acc[mt][nt] = __builtin_amdgcn_mfma_f32_16x16x32_bf16(af[mt], bfr[nt], acc[mt][nt], 0, 0, 0);
        __syncthreads();
        cur ^= 1;
    }

    float bl[2];
#pragma unroll
    for (int nt = 0; nt < 2; nt++) bl[nt] = bias[Nb + wn * 32 + nt * 16 + qc];
#pragma unroll
    for (int mt = 0; mt < 4; mt++) {
#pragma unroll
        for (int nt = 0; nt < 2; nt++) {
            const int m0 = Mb + wm * 64 + mt * 16 + g * 4;
            const int n  = Nb + wn * 32 + nt * 16 + qc;
            f32x4 v = acc[mt][nt];
            v = v + bl[nt];
            if (EPI == 0) {
                const int bb = m0 >> 11, s0 = m0 & 2047;
                const int hh = n >> 6, dh = n & 63;
                uint2 p2;
                p2.x = cvt_pk_bf16(v[0], v[1]);
                p2.y = cvt_pk_bf16(v[2], v[3]);
                *(uint2*)((short*)Cout + (size_t)((bb * 16 + hh) * 64 + dh) * 2048 + s0) = p2;
            } else {
                float* C = (float*)Cout;
#pragma unroll
                for (int i = 0; i < 4; i++) C[(size_t)(m0 + i) * 1024 + n] = v[i];
            }
        }
    }
}

// ---------------------------------------------------------------------------
// Fused MFMA flash attention (v6): LDS double-buffer staged ENTIRELY via
// global_load_lds (async DMA, zero staging VALU).  V tile stored TRANSPOSED
// as [8 key-chunk][64 dh] 16B slots: K=16 A-frag ds_read_b64 hits the exact
// 4-dwords/bank floor (conflict-free), and each global 16B chunk lands in one
// contiguous LDS slot.  Z tile [64][32] linear (already at b128 floor).
// 16 queries/wave, 64 q/block; one barrier/iter (implicit vmcnt drain).
// ---------------------------------------------------------------------------
__global__ __launch_bounds__(256, 4) void attn_mfma6(const short* __restrict__ ZAg,
                                                     const short* __restrict__ ZBg,
                                                     const short* __restrict__ Vt,
                                                     short* __restrict__ AOb) {
    __shared__ short Vs[2][4096];   // [j 0..7][dh 0..63] 16B slots = 8KB/buf
    __shared__ short Zs[2][2048];   // [row 0..63][32 shorts] = 4KB/buf
    const int tid = threadIdx.x;
    const int wv = tid >> 6, l = tid & 63, g = l >> 4, qc = l & 15;
    // XCD-aware bijective swizzle of 1024 blocks (1024 % 8 == 0)
    const int lin = blockIdx.x;
    const int work = (lin & 7) * 128 + (lin >> 3);
    const int qb = work & 31, h = (work >> 5) & 15, b = work >> 9;
    const int bh = b * 16 + h;
    const int q0 = qb * 64 + wv * 16;

    const short* ZAb = ZAg + (size_t)bh * (2048 * 32);
    const short* ZBb = ZBg + (size_t)bh * (2048 * 32);
    const short* Vb  = Vt  + (size_t)bh * (64 * 2048);

    const short8 zq = *(const short8*)(ZBb + (size_t)(q0 + qc) * 32 + g * 8);

    union { unsigned u[2]; short4t s4; } ones4;
    ones4.u[0] = ones4.u[1] = (qc == 0) ? 0x3F803F80u : 0u;  // A row 0 = ones

    f32x4 acc[4] = {};
    f32x4 accl = {};

    // staging: 3 global_load_lds per thread.
    //  V slot s = j*64 + dh; this thread handles s = wv*64+l (j=wv, dh=l) and
    //  s+256 (j=wv+4).  Z slot s = row*4 + chunk; thread handles s = wv*64+l.
    const short* gvb = Vb + (size_t)l * 2048 + wv * 8;     // + kb (and +32 for j=wv+4)
    short* lv = &Vs[0][0] + (size_t)(wv * 64 + l) * 8;
    short* lz = &Zs[0][0] + (size_t)(wv * 64 + l) * 8;
    const int zrow = wv * 16 + (l >> 2), zch = l & 3;

    auto stage = [&](int buf, int kb) {
        const short* gv = gvb + kb;
        short* lvb = lv + buf * 4096;
        __builtin_amdgcn_global_load_lds((const AS1 void*)gv, (AS3 void*)lvb, 16, 0, 0);
        __builtin_amdgcn_global_load_lds((const AS1 void*)(gv + 32), (AS3 void*)(lvb + 2048), 16, 0, 0);
        const short* gz = ZAb + (size_t)(kb + zrow) * 32 + zch * 8;
        __builtin_amdgcn_global_load_lds((const AS1 void*)gz, (AS3 void*)(lz + buf * 2048), 16, 0, 0);
    };

    // per-lane read bases (all further offsets are compile-time immediates)
    const int vrd = (((g >> 1) * 64 + qc) * 8) + (g & 1) * 4;  // + kt*1024 + mt*128
    const int zrd = qc * 32 + g * 8;                            // + kt*512

    stage(0, 0);
    __syncthreads();
    int cur = 0;
#pragma unroll 1
    for (int kb = 0; kb < 2048; kb += 64) {
        if (kb + 64 < 2048) stage(cur ^ 1, kb + 64);   // async, drained at barrier

        const short* Zc = &Zs[cur][0];
        const short* Vc = &Vs[cur][0];

        short8 zk[4];
#pragma unroll
        for (int kt = 0; kt < 4; kt++)
            zk[kt] = *(const short8*)(Zc + zrd + kt * 512);

        const f32x4 z4 = {0.f, 0.f, 0.f, 0.f};
        f32x4 S[4];
        __builtin_amdgcn_s_setprio(1);
#pragma unroll
        for (int kt = 0; kt < 4; kt++)
            S[kt] = __builtin_amdgcn_mfma_f32_16x16x32_bf16(zk[kt], zq, z4, 0, 0, 0);
        __builtin_amdgcn_s_setprio(0);

        // p = exp2(min(S,0)); pack -> per-kt B-fragment (D-layout == B-frag)
        unsigned pk[4][2];
#pragma unroll
        for (int kt = 0; kt < 4; kt++) {
            const float p0 = exp2_fast(fminf(S[kt][0], 0.f));
            const float p1 = exp2_fast(fminf(S[kt][1], 0.f));
            const float p2 = exp2_fast(fminf(S[kt][2], 0.f));
            const float p3 = exp2_fast(fminf(S[kt][3], 0.f));
            pk[kt][0] = cvt_pk_bf16(p0, p1);
            pk[kt][1] = cvt_pk_bf16(p2, p3);
        }

        // PV + l via K=16 MFMAs (B = packed P directly; A = V^T frag from LDS)
        __builtin_amdgcn_s_setprio(1);
#pragma unroll
        for (int kt = 0; kt < 4; kt++) {
            union { unsigned u[2]; short4t s4; } pb;
            pb.u[0] = pk[kt][0];
            pb.u[1] = pk[kt][1];
            accl = mfma_k16(ones4.s4, pb.s4, accl);
#pragma unroll
            for (int mt = 0; mt < 4; mt++)
                acc[mt] = mfma_k16(*(const short4t*)(Vc + vrd + kt * 1024 + mt * 128),
                                   pb.s4, acc[mt]);
        }
        __builtin_amdgcn_s_setprio(0);

        __syncthreads();
        cur ^= 1;
    }

    // epilogue: l sits at D(row0,col qc) = lane qc, reg 0
    const float lv2 = __shfl(accl[0], qc, 64);
    const float inv = 1.f / lv2;
    const size_t row = (size_t)(b * 2048 + q0 + qc) * 1024 + h * 64;
#pragma unroll
    for (int mt = 0; mt < 4; mt++) {
        uint2 o;
        o.x = cvt_pk_bf16(acc[mt][0] * inv, acc[mt][1] * inv);
        o.y = cvt_pk_bf16(acc[mt][2] * inv, acc[mt][3] * inv);
        *(uint2*)(AOb + row + mt * 16 + g * 4) = o;
    }
}

// ---------------------------------------------------------------------------
// updated_coords = hsb(bf16) @ Wnb.T + bn via MFMA.  M=4096, N=16, K=1024.
// Runs BEFORE attn overwrites hsb (AOb alias).
// ---------------------------------------------------------------------------
__global__ __launch_bounds__(256) void coords_mfma(const short* __restrict__ A,
                                                   const short* __restrict__ Wnb,
                                                   const float* __restrict__ bn,
                                                   float* __restrict__ out1) {
    __shared__ float red[4][16][16];
    const int tid = threadIdx.x;
    const int wv = tid >> 6, l = tid & 63, g = l >> 4, qc = l & 15;
    const int m0 = blockIdx.x * 16;
    const int k0 = wv * 256;
    f32x4 acc = {};
#pragma unroll
    for (int kk = 0; kk < 256; kk += 32) {
        const short8 af = *(const short8*)(A + (size_t)(m0 + qc) * 1024 + k0 + kk + g * 8);
        const short8 bf = *(const short8*)(Wnb + (size_t)qc * 1024 + k0 + kk + g * 8);
        acc = __builtin_amdgcn_mfma_f32_16x16x32_bf16(af, bf, acc, 0, 0, 0);
    }
#pragma unroll
    for (int i2 = 0; i2 < 4; i2++) red[wv][g * 4 + i2][qc] = acc[i2];
    __syncthreads();
    const int r = tid >> 4, c = tid & 15;
    const float s = red[0][r][c] + red[1][r][c] + red[2][r][c] + red[3][r][c] + bn[c];
    out1[(size_t)(m0 + r) * 16 + c] = s;
}

// ---------------------------------------------------------------------------
extern "C" void kernel_launch(void* const* d_in, const int* in_sizes, int n_in,
                              void* d_out, int out_size, void* d_ws, size_t ws_size,
                              hipStream_t stream) {
    (void)in_sizes; (void)n_in; (void)out_size; (void)ws_size;
    const float* hidden = (const float*)d_in[0];
    const float* coords = (const float*)d_in[1];
    const float* Wv = (const float*)d_in[2];
    const float* bv = (const float*)d_in[3];
    const float* Wc = (const float*)d_in[4];
    const float* bc = (const float*)d_in[5];
    const float* Wn = (const float*)d_in[6];
    const float* bn = (const float*)d_in[7];
    const float* Wo = (const float*)d_in[8];
    const float* bo = (const float*)d_in[9];
    const float* gamma = (const float*)d_in[10];

    char* wsb = (char*)d_ws;
    short* hsb = (short*)(wsb);                    // 0..8 MB  [4096,1024] bf16
    short* AOb = hsb;                              // aliases hsb (hsb dead after coords_mfma)
    short* Wvb = (short*)(wsb + (8 << 20));        // 8..10 MB
    short* Wob = (short*)(wsb + (10 << 20));       // 10..12 MB
    short* Vt  = (short*)(wsb + (12 << 20));       // 12..20 MB [b,h,dh,s] bf16
    short* ZA  = (short*)(wsb + (20 << 20));       // 20..24 MB [b,h,s,32] bf16
    short* ZB  = (short*)(wsb + (24 << 20));       // 24..28 MB [b,h,s,32] bf16
    short* Wnb = (short*)(wsb + (28 << 20));       // 28 MB + 32 KB [16,1024] bf16

    float* out_hidden = (float*)d_out;             // [B,S,D]
    float* out_coords = out_hidden + 4194304;      // [B,S,CD]

    f2bf_kernel<<<2048, 256, 0, stream>>>(hidden, hsb, 524288);
    f2bfW<<<1032, 256, 0, stream>>>(Wv, Wo, Wn, Wvb, Wob, Wnb);
    zker3<<<4096, 256, 0, stream>>>(coords, Wc, bc, gamma, ZA, ZB);
    gemm_mfma<0><<<dim3(16, 32), 256, 0, stream>>>(hsb, Wvb, bv, (void*)Vt);
    coords_mfma<<<256, 256, 0, stream>>>(hsb, Wnb, bn, out_coords);
    attn_mfma6<<<1024, 256, 0, stream>>>(ZA, ZB, Vt, AOb);
    gemm_mfma<1><<<dim3(16, 32), 256, 0, stream>>>(AOb, Wob, bo, (void*)out_hidden);
}

// Round 9
// 108.175 us; speedup vs baseline: 2.9687x; 1.1004x over previous
//
#include <hip/hip_runtime.h>
#include <math.h>

// Problem constants: B=2, S=2048, D=1024, H=16, DC=16, DH=64
typedef short short8 __attribute__((ext_vector_type(8)));
typedef short short4t __attribute__((ext_vector_type(4)));
typedef float f32x4  __attribute__((ext_vector_type(4)));

#define AS1 __attribute__((address_space(1)))
#define AS3 __attribute__((address_space(3)))

__device__ __forceinline__ unsigned cvt_pk_bf16(float lo, float hi) {
    unsigned r;
    asm("v_cvt_pk_bf16_f32 %0, %1, %2" : "=v"(r) : "v"(lo), "v"(hi));
    return r;
}
__device__ __forceinline__ unsigned f2bf_rne(float x) {
    unsigned u = __float_as_uint(x);
    return (u + 0x7fffu + ((u >> 16) & 1u)) >> 16;
}
__device__ __forceinline__ float exp2_fast(float x) {   // v_exp_f32 computes 2^x
    float r;
    asm("v_exp_f32 %0, %1" : "=v"(r) : "v"(x));
    return r;
}
// 16x16x16 bf16 MFMA (K=16): B-frag layout matches the 16x16 D-layout of the
// score MFMA, so P needs NO cross-lane redistribution before PV.
__device__ __forceinline__ f32x4 mfma_k16(short4t a, short4t b, f32x4 c) {
#if __has_builtin(__builtin_amdgcn_mfma_f32_16x16x16bf16_1k)
    return __builtin_amdgcn_mfma_f32_16x16x16bf16_1k(a, b, c, 0, 0, 0);
#else
    asm volatile("v_mfma_f32_16x16x16_bf16 %0, %1, %2, %0" : "+v"(c) : "v"(a), "v"(b));
    return c;
#endif
}

// ---------------------------------------------------------------------------
// fp32 -> bf16 bulk convert (8 elems/thread)
// ---------------------------------------------------------------------------
__global__ __launch_bounds__(256) void f2bf_kernel(const float* __restrict__ in,
                                                   short* __restrict__ out, int n8) {
    const int i = blockIdx.x * 256 + threadIdx.x;
    if (i >= n8) return;
    const float4 a = ((const float4*)in)[2 * i];
    const float4 b = ((const float4*)in)[2 * i + 1];
    uint4 r;
    r.x = cvt_pk_bf16(a.x, a.y);
    r.y = cvt_pk_bf16(a.z, a.w);
    r.z = cvt_pk_bf16(b.x, b.y);
    r.w = cvt_pk_bf16(b.z, b.w);
    ((uint4*)out)[i] = r;
}

// Wv, Wo, Wn weight converts in one launch (grid 1032)
__global__ __launch_bounds__(256) void f2bfW(const float* __restrict__ Wv,
                                             const float* __restrict__ Wo,
                                             const float* __restrict__ Wn,
                                             short* __restrict__ Wvb,
                                             short* __restrict__ Wob,
                                             short* __restrict__ Wnb) {
    const int i = blockIdx.x * 256 + threadIdx.x;
    const float* src;
    short* dst;
    int ii;
    if (i < 131072)      { src = Wv; dst = Wvb; ii = i; }
    else if (i < 262144) { src = Wo; dst = Wob; ii = i - 131072; }
    else                 { src = Wn; dst = Wnb; ii = i - 262144; }
    const float4 a = ((const float4*)src)[2 * ii];
    const float4 b = ((const float4*)src)[2 * ii + 1];
    uint4 r;
    r.x = cvt_pk_bf16(a.x, a.y);
    r.y = cvt_pk_bf16(a.z, a.w);
    r.z = cvt_pk_bf16(b.x, b.y);
    r.w = cvt_pk_bf16(b.z, b.w);
    ((uint4*)dst)[ii] = r;
}

// ---------------------------------------------------------------------------
// z = coords @ Wc.T + bc, per head h with ch = -softplus(gamma_h)*log2(e):
//   ZA[b,h,s,32] = [z(16), zsq, 1, 0...]          (keys / A-operand)
//   ZB[b,h,s,32] = [-2*ch*z(16), ch, ch*zsq, 0..] (queries / B-operand)
// => MFMA(ZA_k, ZB_q) = ch * (zsq_k + zsq_q - 2 z_k.z_q) = exp2 argument.
// ---------------------------------------------------------------------------
__global__ __launch_bounds__(256) void zker3(const float* __restrict__ coords,
                                             const float* __restrict__ Wc,
                                             const float* __restrict__ bc,
                                             const float* __restrict__ gamma,
                                             short* __restrict__ ZA,
                                             short* __restrict__ ZB) {
    const int bs = blockIdx.x;
    const int b = bs >> 11, s = bs & 2047;
    const int tid = threadIdx.x;
    __shared__ float csh[16];
    if (tid < 16) csh[tid] = coords[(size_t)bs * 16 + tid];
    __syncthreads();
    float z = bc[tid];
#pragma unroll
    for (int k = 0; k < 16; k++) z = fmaf(csh[k], Wc[tid * 16 + k], z);
    const unsigned ub = f2bf_rne(z);
    const float zb = __uint_as_float(ub << 16);
    float sq = zb * zb;
    sq += __shfl_xor(sq, 1, 64);
    sq += __shfl_xor(sq, 2, 64);
    sq += __shfl_xor(sq, 4, 64);
    sq += __shfl_xor(sq, 8, 64);
    const int h = tid >> 4, c = tid & 15;
    const float gm = gamma[h];
    const float sp = fmaxf(gm, 0.f) + log1pf(__expf(-fabsf(gm)));  // softplus
    const float ch = -sp * 1.4426950408889634f;                    // -g*log2(e)
    const size_t row = ((size_t)(b * 16 + h) * 2048 + s) * 32;
    ZA[row + c] = (short)ub;
    ZA[row + 16 + c] = (c == 0) ? (short)f2bf_rne(sq)
                                : (c == 1 ? (short)0x3F80 : (short)0);
    ZB[row + c] = (short)f2bf_rne(-2.f * ch * zb);
    ZB[row + 16 + c] = (c == 0) ? (short)f2bf_rne(ch)
                                : (c == 1 ? (short)f2bf_rne(ch * sq) : (short)0);
}

// ---------------------------------------------------------------------------
// bf16 MFMA GEMM: C[m,n] = sum_k A[m,k]*W[n,k] + bias[n].  M=4096,N=1024,K=1024
// 128x64 tile, BK=64 (16 MFMAs per barrier), 4 waves (2x2 of 64x32), LDS
// double-buffer via global_load_lds w16.  Rows are 128B-stride so chunk-XOR
// swizzle `slot = chunk ^ (row&7)` (applied via pre-swizzled global source,
// rule #21) makes the b128 frag reads conflict-free (2 lanes/slot = free).
// EPI=0: write V^T bf16 [b,h,dh,s];  EPI=1: fp32 row-major [m,n]
// ---------------------------------------------------------------------------
template <int EPI>
__global__ __launch_bounds__(256) void gemm_mfma(const short* __restrict__ A,
                                                 const short* __restrict__ W,
                                                 const float* __restrict__ bias,
                                                 void* __restrict__ Cout) {
    __shared__ short As[2][128][64];
    __shared__ short Bs[2][64][64];
    const int tid = threadIdx.x;
    const int wv = tid >> 6, l = tid & 63, g = l >> 4, qc = l & 15;
    const int wm = wv >> 1, wn = wv & 1;
    const int Mb = blockIdx.y * 128, Nb = blockIdx.x * 64;

    auto stage = [&](int buf, int k0) {
#pragma unroll
        for (int i = 0; i < 4; i++) {                    // A: 1024 chunks, 4/thread
            const int c = i * 256 + tid;
            const int r = c >> 3, jp = c & 7;
            const int js = jp ^ (r & 7);                 // pre-swizzled source
            const short* gsA = A + (size_t)(Mb + r) * 1024 + k0 + js * 8;
            short* ldsA = &As[buf][0][0] + (size_t)(i * 256 + wv * 64) * 8;
            __builtin_amdgcn_global_load_lds((const AS1 void*)gsA, (AS3 void*)ldsA, 16, 0, 0);
        }
#pragma unroll
        for (int i = 0; i < 2; i++) {                    // B: 512 chunks, 2/thread
            const int c = i * 256 + tid;
            const int r = c >> 3, jp = c & 7;
            const int js = jp ^ (r & 7);
            const short* gsB = W + (size_t)(Nb + r) * 1024 + k0 + js * 8;
            short* ldsB = &Bs[buf][0][0] + (size_t)(i * 256 + wv * 64) * 8;
            __builtin_amdgcn_global_load_lds((const AS1 void*)gsB, (AS3 void*)ldsB, 16, 0, 0);
        }
    };

    f32x4 acc[4][2] = {};
    stage(0, 0);
    __syncthreads();
    int cur = 0;
#pragma unroll 1
    for (int kb = 0; kb < 16; kb++) {
        if (kb < 15) stage(cur ^ 1, (kb + 1) * 64);
#pragma unroll
        for (int ks = 0; ks < 2; ks++) {
            const int cs = ((ks * 4 + g) ^ (qc & 7)) * 8;   // swizzled read slot
            short8 af[4], bfr[2];
#pragma unroll
            for (int mt = 0; mt < 4; mt++)
                af[mt] = *(const short8*)&As[cur][wm * 64 + mt * 16 + qc][cs];
#pragma unroll
            for (int nt = 0; nt < 2; nt++)
                bfr[nt] = *(const short8*)&Bs[cur][wn * 32 + nt * 16 + qc][cs];
#pragma unroll
            for (int mt = 0; mt < 4; mt++)
#pragma unroll
                for (int nt = 0; nt < 2; nt++)
                    acc[mt][nt] = __builtin_amdgcn_mfma_f32_16x16x32_bf16(af[mt], bfr[nt], acc[mt][nt], 0, 0, 0);
        }
        __syncthreads();
        cur ^= 1;
    }

    float bl[2];
#pragma unroll
    for (int nt = 0; nt < 2; nt++) bl[nt] = bias[Nb + wn * 32 + nt * 16 + qc];
#pragma unroll
    for (int mt = 0; mt < 4; mt++) {
#pragma unroll
        for (int nt = 0; nt < 2; nt++) {
            const int m0 = Mb + wm * 64 + mt * 16 + g * 4;
            const int n  = Nb + wn * 32 + nt * 16 + qc;
            f32x4 v = acc[mt][nt];
            v = v + bl[nt];
            if (EPI == 0) {
                const int bb = m0 >> 11, s0 = m0 & 2047;
                const int hh = n >> 6, dh = n & 63;
                uint2 p2;
                p2.x = cvt_pk_bf16(v[0], v[1]);
                p2.y = cvt_pk_bf16(v[2], v[3]);
                *(uint2*)((short*)Cout + (size_t)((bb * 16 + hh) * 64 + dh) * 2048 + s0) = p2;
            } else {
                float* C = (float*)Cout;
#pragma unroll
                for (int i = 0; i < 4; i++) C[(size_t)(m0 + i) * 1024 + n] = v[i];
            }
        }
    }
}

// ---------------------------------------------------------------------------
// Fused MFMA flash attention (v7 = v6 + T15 double-pipeline):
// While PV(i)'s MFMAs run, S(i+1)+exp2+pack execute on the VALU pipe —
// the two streams are data-independent, so MFMA and VALU co-issue instead of
// serializing (v6's measured 35% Mfma + 42% VALU with no overlap).
// Z staged 2 tiles ahead in a 4-deep ring; V double-buffered; all staging
// via global_load_lds (async DMA).  No score clamp: gamma=softplus inputs
// give scores in [-0.5, 0]; bf16 error <= +0.01 in the exp2 arg, normalized
// out by l.  16 q/wave, 64 q/block, 1024 blocks, XCD-swizzled.
// ---------------------------------------------------------------------------
__global__ __launch_bounds__(256, 4) void attn_mfma7(const short* __restrict__ ZAg,
                                                     const short* __restrict__ ZBg,
                                                     const short* __restrict__ Vt,
                                                     short* __restrict__ AOb) {
    __shared__ short Vs[2][4096];   // V tile [j 0..7][dh 0..63] 16B slots, dbuf
    __shared__ short Zs[4][2048];   // Z tile [row 0..63][32], 4-deep ring
    const int tid = threadIdx.x;
    const int wv = tid >> 6, l = tid & 63, g = l >> 4, qc = l & 15;
    const int lin = blockIdx.x;
    const int work = (lin & 7) * 128 + (lin >> 3);   // bijective, 1024 % 8 == 0
    const int qb = work & 31, h = (work >> 5) & 15, b = work >> 9;
    const int bh = b * 16 + h;
    const int q0 = qb * 64 + wv * 16;

    const short* ZAb = ZAg + (size_t)bh * (2048 * 32);
    const short* ZBb = ZBg + (size_t)bh * (2048 * 32);
    const short* Vb  = Vt  + (size_t)bh * (64 * 2048);

    const short8 zq = *(const short8*)(ZBb + (size_t)(q0 + qc) * 32 + g * 8);

    union { unsigned u[2]; short4t s4; } ones4;
    ones4.u[0] = ones4.u[1] = (qc == 0) ? 0x3F803F80u : 0u;  // A row 0 = ones

    f32x4 acc[4] = {};
    f32x4 accl = {};

    // staging bases (thread-linear dests per rule #21)
    const short* gvb = Vb + (size_t)l * 2048 + wv * 8;
    short* lvd = &Vs[0][0] + (size_t)(wv * 64 + l) * 8;
    short* lzd = &Zs[0][0] + (size_t)(wv * 64 + l) * 8;
    const int zrow = wv * 16 + (l >> 2), zch = l & 3;

    auto stageV = [&](int buf, int kb) {
        const short* gv = gvb + kb;
        short* lvb = lvd + buf * 4096;
        __builtin_amdgcn_global_load_lds((const AS1 void*)gv, (AS3 void*)lvb, 16, 0, 0);
        __builtin_amdgcn_global_load_lds((const AS1 void*)(gv + 32), (AS3 void*)(lvb + 2048), 16, 0, 0);
    };
    auto stageZ = [&](int buf, int kb) {
        const short* gz = ZAb + (size_t)(kb + zrow) * 32 + zch * 8;
        __builtin_amdgcn_global_load_lds((const AS1 void*)gz, (AS3 void*)(lzd + buf * 2048), 16, 0, 0);
    };

    // per-lane read bases (further offsets are compile-time immediates)
    const int vrd = (((g >> 1) * 64 + qc) * 8) + (g & 1) * 4;  // + kt*1024 + mt*128
    const int zrd = qc * 32 + g * 8;                            // + kt*512

    // S(tile)+exp2+pack from the Z ring (the VALU stream of the pipeline)
    auto computeP = [&](int zbuf, unsigned pko[4][2]) {
        const short* Zc = &Zs[zbuf][0];
        short8 zk[4];
#pragma unroll
        for (int kt = 0; kt < 4; kt++)
            zk[kt] = *(const short8*)(Zc + zrd + kt * 512);
        const f32x4 z4 = {0.f, 0.f, 0.f, 0.f};
#pragma unroll
        for (int kt = 0; kt < 4; kt++) {
            const f32x4 S = __builtin_amdgcn_mfma_f32_16x16x32_bf16(zk[kt], zq, z4, 0, 0, 0);
            pko[kt][0] = cvt_pk_bf16(exp2_fast(S[0]), exp2_fast(S[1]));
            pko[kt][1] = cvt_pk_bf16(exp2_fast(S[2]), exp2_fast(S[3]));
        }
    };

    // prologue: V(0), Z(0), Z(1); compute pk(0)
    stageV(0, 0);
    stageZ(0, 0);
    stageZ(1, 64);
    __syncthreads();

    unsigned pk[4][2];
    computeP(0, pk);

    int cur = 0;
#pragma unroll 1
    for (int i = 0; i < 32; i++) {
        const int kb = i * 64;
        if (i < 31) stageV(cur ^ 1, kb + 64);
        if (i < 30) stageZ((i + 2) & 3, kb + 128);

        // pipeline: S/exp2/pack of tile i+1 (VALU) overlapped with PV of i (MFMA)
        unsigned pknext[4][2];
        computeP((i + 1) & 3, pknext);   // last iter: result unused (reads old buf, no race)

        const short* Vc = &Vs[cur][0];
        __builtin_amdgcn_s_setprio(1);
#pragma unroll
        for (int kt = 0; kt < 4; kt++) {
            union { unsigned u[2]; short4t s4; } pb;
            pb.u[0] = pk[kt][0];
            pb.u[1] = pk[kt][1];
            accl = mfma_k16(ones4.s4, pb.s4, accl);
#pragma unroll
            for (int mt = 0; mt < 4; mt++)
                acc[mt] = mfma_k16(*(const short4t*)(Vc + vrd + kt * 1024 + mt * 128),
                                   pb.s4, acc[mt]);
        }
        __builtin_amdgcn_s_setprio(0);

#pragma unroll
        for (int kt = 0; kt < 4; kt++) {
            pk[kt][0] = pknext[kt][0];
            pk[kt][1] = pknext[kt][1];
        }

        __syncthreads();
        cur ^= 1;
    }

    // epilogue: l sits at D(row0,col qc) = lane qc, reg 0
    const float lv2 = __shfl(accl[0], qc, 64);
    const float inv = 1.f / lv2;
    const size_t row = (size_t)(b * 2048 + q0 + qc) * 1024 + h * 64;
#pragma unroll
    for (int mt = 0; mt < 4; mt++) {
        uint2 o;
        o.x = cvt_pk_bf16(acc[mt][0] * inv, acc[mt][1] * inv);
        o.y = cvt_pk_bf16(acc[mt][2] * inv, acc[mt][3] * inv);
        *(uint2*)(AOb + row + mt * 16 + g * 4) = o;
    }
}

// ---------------------------------------------------------------------------
// updated_coords = hsb(bf16) @ Wnb.T + bn via MFMA.  M=4096, N=16, K=1024.
// Runs BEFORE attn overwrites hsb (AOb alias).
// ---------------------------------------------------------------------------
__global__ __launch_bounds__(256) void coords_mfma(const short* __restrict__ A,
                                                   const short* __restrict__ Wnb,
                                                   const float* __restrict__ bn,
                                                   float* __restrict__ out1) {
    __shared__ float red[4][16][16];
    const int tid = threadIdx.x;
    const int wv = tid >> 6, l = tid & 63, g = l >> 4, qc = l & 15;
    const int m0 = blockIdx.x * 16;
    const int k0 = wv * 256;
    f32x4 acc = {};
#pragma unroll
    for (int kk = 0; kk < 256; kk += 32) {
        const short8 af = *(const short8*)(A + (size_t)(m0 + qc) * 1024 + k0 + kk + g * 8);
        const short8 bf = *(const short8*)(Wnb + (size_t)qc * 1024 + k0 + kk + g * 8);
        acc = __builtin_amdgcn_mfma_f32_16x16x32_bf16(af, bf, acc, 0, 0, 0);
    }
#pragma unroll
    for (int i2 = 0; i2 < 4; i2++) red[wv][g * 4 + i2][qc] = acc[i2];
    __syncthreads();
    const int r = tid >> 4, c = tid & 15;
    const float s = red[0][r][c] + red[1][r][c] + red[2][r][c] + red[3][r][c] + bn[c];
    out1[(size_t)(m0 + r) * 16 + c] = s;
}

// ---------------------------------------------------------------------------
extern "C" void kernel_launch(void* const* d_in, const int* in_sizes, int n_in,
                              void* d_out, int out_size, void* d_ws, size_t ws_size,
                              hipStream_t stream) {
    (void)in_sizes; (void)n_in; (void)out_size; (void)ws_size;
    const float* hidden = (const float*)d_in[0];
    const float* coords = (const float*)d_in[1];
    const float* Wv = (const float*)d_in[2];
    const float* bv = (const float*)d_in[3];
    const float* Wc = (const float*)d_in[4];
    const float* bc = (const float*)d_in[5];
    const float* Wn = (const float*)d_in[6];
    const float* bn = (const float*)d_in[7];
    const float* Wo = (const float*)d_in[8];
    const float* bo = (const float*)d_in[9];
    const float* gamma = (const float*)d_in[10];

    char* wsb = (char*)d_ws;
    short* hsb = (short*)(wsb);                    // 0..8 MB  [4096,1024] bf16
    short* AOb = hsb;                              // aliases hsb (hsb dead after coords_mfma)
    short* Wvb = (short*)(wsb + (8 << 20));        // 8..10 MB
    short* Wob = (short*)(wsb + (10 << 20));       // 10..12 MB
    short* Vt  = (short*)(wsb + (12 << 20));       // 12..20 MB [b,h,dh,s] bf16
    short* ZA  = (short*)(wsb + (20 << 20));       // 20..24 MB [b,h,s,32] bf16
    short* ZB  = (short*)(wsb + (24 << 20));       // 24..28 MB [b,h,s,32] bf16
    short* Wnb = (short*)(wsb + (28 << 20));       // 28 MB + 32 KB [16,1024] bf16

    float* out_hidden = (float*)d_out;             // [B,S,D]
    float* out_coords = out_hidden + 4194304;      // [B,S,CD]

    f2bf_kernel<<<2048, 256, 0, stream>>>(hidden, hsb, 524288);
    f2bfW<<<1032, 256, 0, stream>>>(Wv, Wo, Wn, Wvb, Wob, Wnb);
    zker3<<<4096, 256, 0, stream>>>(coords, Wc, bc, gamma, ZA, ZB);
    gemm_mfma<0><<<dim3(16, 32), 256, 0, stream>>>(hsb, Wvb, bv, (void*)Vt);
    coords_mfma<<<256, 256, 0, stream>>>(hsb, Wnb, bn, out_coords);
    attn_mfma7<<<1024, 256, 0, stream>>>(ZA, ZB, Vt, AOb);
    gemm_mfma<1><<<dim3(16, 32), 256, 0, stream>>>(AOb, Wob, bo, (void*)out_hidden);
}

// Round 10
// 107.024 us; speedup vs baseline: 3.0006x; 1.0108x over previous
//
#include <hip/hip_runtime.h>
#include <math.h>

// Problem constants: B=2, S=2048, D=1024, H=16, DC=16, DH=64
typedef short short8 __attribute__((ext_vector_type(8)));
typedef short short4t __attribute__((ext_vector_type(4)));
typedef float f32x4  __attribute__((ext_vector_type(4)));

#define AS1 __attribute__((address_space(1)))
#define AS3 __attribute__((address_space(3)))

__device__ __forceinline__ unsigned cvt_pk_bf16(float lo, float hi) {
    unsigned r;
    asm("v_cvt_pk_bf16_f32 %0, %1, %2" : "=v"(r) : "v"(lo), "v"(hi));
    return r;
}
__device__ __forceinline__ unsigned f2bf_rne(float x) {
    unsigned u = __float_as_uint(x);
    return (u + 0x7fffu + ((u >> 16) & 1u)) >> 16;
}
__device__ __forceinline__ float exp2_fast(float x) {   // v_exp_f32 computes 2^x
    float r;
    asm("v_exp_f32 %0, %1" : "=v"(r) : "v"(x));
    return r;
}
// 16x16x16 bf16 MFMA (K=16): B-frag layout matches the 16x16 D-layout of the
// score MFMA, so P needs NO cross-lane redistribution before PV.
__device__ __forceinline__ f32x4 mfma_k16(short4t a, short4t b, f32x4 c) {
#if __has_builtin(__builtin_amdgcn_mfma_f32_16x16x16bf16_1k)
    return __builtin_amdgcn_mfma_f32_16x16x16bf16_1k(a, b, c, 0, 0, 0);
#else
    asm volatile("v_mfma_f32_16x16x16_bf16 %0, %1, %2, %0" : "+v"(c) : "v"(a), "v"(b));
    return c;
#endif
}

// ---------------------------------------------------------------------------
// fp32 -> bf16 bulk convert (8 elems/thread)
// ---------------------------------------------------------------------------
__global__ __launch_bounds__(256) void f2bf_kernel(const float* __restrict__ in,
                                                   short* __restrict__ out, int n8) {
    const int i = blockIdx.x * 256 + threadIdx.x;
    if (i >= n8) return;
    const float4 a = ((const float4*)in)[2 * i];
    const float4 b = ((const float4*)in)[2 * i + 1];
    uint4 r;
    r.x = cvt_pk_bf16(a.x, a.y);
    r.y = cvt_pk_bf16(a.z, a.w);
    r.z = cvt_pk_bf16(b.x, b.y);
    r.w = cvt_pk_bf16(b.z, b.w);
    ((uint4*)out)[i] = r;
}

// Wv, Wo, Wn weight converts in one launch (grid 1032)
__global__ __launch_bounds__(256) void f2bfW(const float* __restrict__ Wv,
                                             const float* __restrict__ Wo,
                                             const float* __restrict__ Wn,
                                             short* __restrict__ Wvb,
                                             short* __restrict__ Wob,
                                             short* __restrict__ Wnb) {
    const int i = blockIdx.x * 256 + threadIdx.x;
    const float* src;
    short* dst;
    int ii;
    if (i < 131072)      { src = Wv; dst = Wvb; ii = i; }
    else if (i < 262144) { src = Wo; dst = Wob; ii = i - 131072; }
    else                 { src = Wn; dst = Wnb; ii = i - 262144; }
    const float4 a = ((const float4*)src)[2 * ii];
    const float4 b = ((const float4*)src)[2 * ii + 1];
    uint4 r;
    r.x = cvt_pk_bf16(a.x, a.y);
    r.y = cvt_pk_bf16(a.z, a.w);
    r.z = cvt_pk_bf16(b.x, b.y);
    r.w = cvt_pk_bf16(b.z, b.w);
    ((uint4*)dst)[ii] = r;
}

// ---------------------------------------------------------------------------
// z = coords @ Wc.T + bc, per head h with ch = -softplus(gamma_h)*log2(e):
//   ZA[b,h,s,32] = [z(16), zsq, 1, 0...]          (keys / A-operand)
//   ZB[b,h,s,32] = [-2*ch*z(16), ch, ch*zsq, 0..] (queries / B-operand)
// => MFMA(ZA_k, ZB_q) = ch * (zsq_k + zsq_q - 2 z_k.z_q) = exp2 argument.
// ---------------------------------------------------------------------------
__global__ __launch_bounds__(256) void zker3(const float* __restrict__ coords,
                                             const float* __restrict__ Wc,
                                             const float* __restrict__ bc,
                                             const float* __restrict__ gamma,
                                             short* __restrict__ ZA,
                                             short* __restrict__ ZB) {
    const int bs = blockIdx.x;
    const int b = bs >> 11, s = bs & 2047;
    const int tid = threadIdx.x;
    __shared__ float csh[16];
    if (tid < 16) csh[tid] = coords[(size_t)bs * 16 + tid];
    __syncthreads();
    float z = bc[tid];
#pragma unroll
    for (int k = 0; k < 16; k++) z = fmaf(csh[k], Wc[tid * 16 + k], z);
    const unsigned ub = f2bf_rne(z);
    const float zb = __uint_as_float(ub << 16);
    float sq = zb * zb;
    sq += __shfl_xor(sq, 1, 64);
    sq += __shfl_xor(sq, 2, 64);
    sq += __shfl_xor(sq, 4, 64);
    sq += __shfl_xor(sq, 8, 64);
    const int h = tid >> 4, c = tid & 15;
    const float gm = gamma[h];
    const float sp = fmaxf(gm, 0.f) + log1pf(__expf(-fabsf(gm)));  // softplus
    const float ch = -sp * 1.4426950408889634f;                    // -g*log2(e)
    const size_t row = ((size_t)(b * 16 + h) * 2048 + s) * 32;
    ZA[row + c] = (short)ub;
    ZA[row + 16 + c] = (c == 0) ? (short)f2bf_rne(sq)
                                : (c == 1 ? (short)0x3F80 : (short)0);
    ZB[row + c] = (short)f2bf_rne(-2.f * ch * zb);
    ZB[row + 16 + c] = (c == 0) ? (short)f2bf_rne(ch)
                                : (c == 1 ? (short)f2bf_rne(ch * sq) : (short)0);
}

// ---------------------------------------------------------------------------
// bf16 MFMA GEMM: C[m,n] = sum_k A[m,k]*W[n,k] + bias[n].  M=4096,N=1024,K=1024
// 128x64 tile, BK=64 (16 MFMAs per barrier), 4 waves (2x2 of 64x32), LDS
// double-buffer via global_load_lds w16, chunk-XOR swizzle via pre-swizzled
// global source (rule #21).
// EPI=0: write V^T bf16 [b,h,dh,s] with the 8B-half swap (dh bit3) so the
//        attention's K=16 A-frag LDS reads are bank-conflict-free.
// EPI=1: fp32 row-major [m,n]
// ---------------------------------------------------------------------------
template <int EPI>
__global__ __launch_bounds__(256) void gemm_mfma(const short* __restrict__ A,
                                                 const short* __restrict__ W,
                                                 const float* __restrict__ bias,
                                                 void* __restrict__ Cout) {
    __shared__ short As[2][128][64];
    __shared__ short Bs[2][64][64];
    const int tid = threadIdx.x;
    const int wv = tid >> 6, l = tid & 63, g = l >> 4, qc = l & 15;
    const int wm = wv >> 1, wn = wv & 1;
    const int Mb = blockIdx.y * 128, Nb = blockIdx.x * 64;

    auto stage = [&](int buf, int k0) {
#pragma unroll
        for (int i = 0; i < 4; i++) {                    // A: 1024 chunks, 4/thread
            const int c = i * 256 + tid;
            const int r = c >> 3, jp = c & 7;
            const int js = jp ^ (r & 7);                 // pre-swizzled source
            const short* gsA = A + (size_t)(Mb + r) * 1024 + k0 + js * 8;
            short* ldsA = &As[buf][0][0] + (size_t)(i * 256 + wv * 64) * 8;
            __builtin_amdgcn_global_load_lds((const AS1 void*)gsA, (AS3 void*)ldsA, 16, 0, 0);
        }
#pragma unroll
        for (int i = 0; i < 2; i++) {                    // B: 512 chunks, 2/thread
            const int c = i * 256 + tid;
            const int r = c >> 3, jp = c & 7;
            const int js = jp ^ (r & 7);
            const short* gsB = W + (size_t)(Nb + r) * 1024 + k0 + js * 8;
            short* ldsB = &Bs[buf][0][0] + (size_t)(i * 256 + wv * 64) * 8;
            __builtin_amdgcn_global_load_lds((const AS1 void*)gsB, (AS3 void*)ldsB, 16, 0, 0);
        }
    };

    f32x4 acc[4][2] = {};
    stage(0, 0);
    __syncthreads();
    int cur = 0;
#pragma unroll 1
    for (int kb = 0; kb < 16; kb++) {
        if (kb < 15) stage(cur ^ 1, (kb + 1) * 64);
#pragma unroll
        for (int ks = 0; ks < 2; ks++) {
            const int cs = ((ks * 4 + g) ^ (qc & 7)) * 8;   // swizzled read slot
            short8 af[4], bfr[2];
#pragma unroll
            for (int mt = 0; mt < 4; mt++)
                af[mt] = *(const short8*)&As[cur][wm * 64 + mt * 16 + qc][cs];
#pragma unroll
            for (int nt = 0; nt < 2; nt++)
                bfr[nt] = *(const short8*)&Bs[cur][wn * 32 + nt * 16 + qc][cs];
#pragma unroll
            for (int mt = 0; mt < 4; mt++)
#pragma unroll
                for (int nt = 0; nt < 2; nt++)
                    acc[mt][nt] = __builtin_amdgcn_mfma_f32_16x16x32_bf16(af[mt], bfr[nt], acc[mt][nt], 0, 0, 0);
        }
        __syncthreads();
        cur ^= 1;
    }

    float bl[2];
#pragma unroll
    for (int nt = 0; nt < 2; nt++) bl[nt] = bias[Nb + wn * 32 + nt * 16 + qc];
#pragma unroll
    for (int mt = 0; mt < 4; mt++) {
#pragma unroll
        for (int nt = 0; nt < 2; nt++) {
            const int m0 = Mb + wm * 64 + mt * 16 + g * 4;
            const int n  = Nb + wn * 32 + nt * 16 + qc;
            f32x4 v = acc[mt][nt];
            v = v + bl[nt];
            if (EPI == 0) {
                const int bb = m0 >> 11, s0 = m0 & 2047;
                const int hh = n >> 6, dh = n & 63;
                const int s0x = s0 ^ (((n >> 3) & 1) << 2);   // 8B-half swap for dh bit3
                uint2 p2;
                p2.x = cvt_pk_bf16(v[0], v[1]);
                p2.y = cvt_pk_bf16(v[2], v[3]);
                *(uint2*)((short*)Cout + (size_t)((bb * 16 + hh) * 64 + dh) * 2048 + s0x) = p2;
            } else {
                float* C = (float*)Cout;
#pragma unroll
                for (int i = 0; i < 4; i++) C[(size_t)(m0 + i) * 1024 + n] = v[i];
            }
        }
    }
}

// ---------------------------------------------------------------------------
// Fused MFMA flash attention (v8 = v7 + conflict-free LDS layouts):
//  * Z tile stored chunk-permuted (chunk(row,g) -> g*16 + (row&15) within each
//    16-row group): lane l's zk read is chunk kt*64+l — a contiguous 1KB wave
//    read, conflict-free by construction.  Permutation applied on the global
//    SOURCE of global_load_lds; LDS dest stays thread-linear (rule #21).
//  * V A-frag b64 reads: 8B-half selector XOR'd with dh bit3 (pre-swapped in
//    Vt by the gemm<0> epilogue) — kills the qc/qc+8 bank aliasing (2-way max).
//  * T15 pipeline: S(i+1)+exp2+pack (VALU) overlaps PV(i) (MFMA).
//  * Score clamp restored (absmax margin).
// 16 q/wave, 64 q/block, 1024 blocks XCD-swizzled, 4 blocks/CU.
// ---------------------------------------------------------------------------
__global__ __launch_bounds__(256, 4) void attn_mfma8(const short* __restrict__ ZAg,
                                                     const short* __restrict__ ZBg,
                                                     const short* __restrict__ Vt,
                                                     short* __restrict__ AOb) {
    __shared__ short Vs[2][4096];   // V tile [j 0..7][dh 0..63] 16B slots, dbuf
    __shared__ short Zs[4][2048];   // Z tile, chunk-permuted, 4-deep ring
    const int tid = threadIdx.x;
    const int wv = tid >> 6, l = tid & 63, g = l >> 4, qc = l & 15;
    const int lin = blockIdx.x;
    const int work = (lin & 7) * 128 + (lin >> 3);   // bijective, 1024 % 8 == 0
    const int qb = work & 31, h = (work >> 5) & 15, b = work >> 9;
    const int bh = b * 16 + h;
    const int q0 = qb * 64 + wv * 16;

    const short* ZAb = ZAg + (size_t)bh * (2048 * 32);
    const short* ZBb = ZBg + (size_t)bh * (2048 * 32);
    const short* Vb  = Vt  + (size_t)bh * (64 * 2048);

    const short8 zq = *(const short8*)(ZBb + (size_t)(q0 + qc) * 32 + g * 8);

    union { unsigned u[2]; short4t s4; } ones4;
    ones4.u[0] = ones4.u[1] = (qc == 0) ? 0x3F803F80u : 0u;  // A row 0 = ones

    f32x4 acc[4] = {};
    f32x4 accl = {};

    // staging bases (thread-linear dests per rule #21)
    const short* gvb = Vb + (size_t)l * 2048 + wv * 8;
    short* lvd = &Vs[0][0] + (size_t)tid * 8;
    short* lzd = &Zs[0][0] + (size_t)tid * 8;
    // Z source permutation: thread tid stages LDS chunk tid; content is
    // (row = z_kt*16 + z_r, 8-short group z_g) of the tile.
    const int z_kt = tid >> 6, z_g = (tid >> 4) & 3, z_r = tid & 15;

    auto stageV = [&](int buf, int kb) {
        const short* gv = gvb + kb;
        short* lvb = lvd + buf * 4096;
        __builtin_amdgcn_global_load_lds((const AS1 void*)gv, (AS3 void*)lvb, 16, 0, 0);
        __builtin_amdgcn_global_load_lds((const AS1 void*)(gv + 32), (AS3 void*)(lvb + 2048), 16, 0, 0);
    };
    auto stageZ = [&](int buf, int kb) {
        const short* gz = ZAb + (size_t)(kb + z_kt * 16 + z_r) * 32 + z_g * 8;
        __builtin_amdgcn_global_load_lds((const AS1 void*)gz, (AS3 void*)(lzd + buf * 2048), 16, 0, 0);
    };

    // per-lane read bases (further offsets are compile-time immediates)
    const int vrd = (((g >> 1) * 64 + qc) * 8) + (((g & 1) ^ ((qc >> 3) & 1)) << 2);
    const int zrd = g * 128 + qc * 8;   // chunk g*16+qc of each 16-row group

    // S(tile)+exp2+pack from the Z ring (the VALU stream of the pipeline)
    auto computeP = [&](int zbuf, unsigned pko[4][2]) {
        const short* Zc = &Zs[zbuf][0];
        short8 zk[4];
#pragma unroll
        for (int kt = 0; kt < 4; kt++)
            zk[kt] = *(const short8*)(Zc + zrd + kt * 512);
        const f32x4 z4 = {0.f, 0.f, 0.f, 0.f};
#pragma unroll
        for (int kt = 0; kt < 4; kt++) {
            const f32x4 S = __builtin_amdgcn_mfma_f32_16x16x32_bf16(zk[kt], zq, z4, 0, 0, 0);
            pko[kt][0] = cvt_pk_bf16(exp2_fast(fminf(S[0], 0.f)), exp2_fast(fminf(S[1], 0.f)));
            pko[kt][1] = cvt_pk_bf16(exp2_fast(fminf(S[2], 0.f)), exp2_fast(fminf(S[3], 0.f)));
        }
    };

    // prologue: V(0), Z(0), Z(1); compute pk(0)
    stageV(0, 0);
    stageZ(0, 0);
    stageZ(1, 64);
    __syncthreads();

    unsigned pk[4][2];
    computeP(0, pk);

    int cur = 0;
#pragma unroll 1
    for (int i = 0; i < 32; i++) {
        const int kb = i * 64;
        if (i < 31) stageV(cur ^ 1, kb + 64);
        if (i < 30) stageZ((i + 2) & 3, kb + 128);

        // pipeline: S/exp2/pack of tile i+1 (VALU) overlapped with PV of i (MFMA)
        unsigned pknext[4][2];
        computeP((i + 1) & 3, pknext);   // last iter: result unused (reads old buf, no race)

        const short* Vc = &Vs[cur][0];
        __builtin_amdgcn_s_setprio(1);
#pragma unroll
        for (int kt = 0; kt < 4; kt++) {
            union { unsigned u[2]; short4t s4; } pb;
            pb.u[0] = pk[kt][0];
            pb.u[1] = pk[kt][1];
            accl = mfma_k16(ones4.s4, pb.s4, accl);
#pragma unroll
            for (int mt = 0; mt < 4; mt++)
                acc[mt] = mfma_k16(*(const short4t*)(Vc + vrd + kt * 1024 + mt * 128),
                                   pb.s4, acc[mt]);
        }
        __builtin_amdgcn_s_setprio(0);

#pragma unroll
        for (int kt = 0; kt < 4; kt++) {
            pk[kt][0] = pknext[kt][0];
            pk[kt][1] = pknext[kt][1];
        }

        __syncthreads();
        cur ^= 1;
    }

    // epilogue: l sits at D(row0,col qc) = lane qc, reg 0
    const float lv2 = __shfl(accl[0], qc, 64);
    const float inv = 1.f / lv2;
    const size_t row = (size_t)(b * 2048 + q0 + qc) * 1024 + h * 64;
#pragma unroll
    for (int mt = 0; mt < 4; mt++) {
        uint2 o;
        o.x = cvt_pk_bf16(acc[mt][0] * inv, acc[mt][1] * inv);
        o.y = cvt_pk_bf16(acc[mt][2] * inv, acc[mt][3] * inv);
        *(uint2*)(AOb + row + mt * 16 + g * 4) = o;
    }
}

// ---------------------------------------------------------------------------
// updated_coords = hsb(bf16) @ Wnb.T + bn via MFMA.  M=4096, N=16, K=1024.
// Runs BEFORE attn overwrites hsb (AOb alias).
// ---------------------------------------------------------------------------
__global__ __launch_bounds__(256) void coords_mfma(const short* __restrict__ A,
                                                   const short* __restrict__ Wnb,
                                                   const float* __restrict__ bn,
                                                   float* __restrict__ out1) {
    __shared__ float red[4][16][16];
    const int tid = threadIdx.x;
    const int wv = tid >> 6, l = tid & 63, g = l >> 4, qc = l & 15;
    const int m0 = blockIdx.x * 16;
    const int k0 = wv * 256;
    f32x4 acc = {};
#pragma unroll
    for (int kk = 0; kk < 256; kk += 32) {
        const short8 af = *(const short8*)(A + (size_t)(m0 + qc) * 1024 + k0 + kk + g * 8);
        const short8 bf = *(const short8*)(Wnb + (size_t)qc * 1024 + k0 + kk + g * 8);
        acc = __builtin_amdgcn_mfma_f32_16x16x32_bf16(af, bf, acc, 0, 0, 0);
    }
#pragma unroll
    for (int i2 = 0; i2 < 4; i2++) red[wv][g * 4 + i2][qc] = acc[i2];
    __syncthreads();
    const int r = tid >> 4, c = tid & 15;
    const float s = red[0][r][c] + red[1][r][c] + red[2][r][c] + red[3][r][c] + bn[c];
    out1[(size_t)(m0 + r) * 16 + c] = s;
}

// ---------------------------------------------------------------------------
extern "C" void kernel_launch(void* const* d_in, const int* in_sizes, int n_in,
                              void* d_out, int out_size, void* d_ws, size_t ws_size,
                              hipStream_t stream) {
    (void)in_sizes; (void)n_in; (void)out_size; (void)ws_size;
    const float* hidden = (const float*)d_in[0];
    const float* coords = (const float*)d_in[1];
    const float* Wv = (const float*)d_in[2];
    const float* bv = (const float*)d_in[3];
    const float* Wc = (const float*)d_in[4];
    const float* bc = (const float*)d_in[5];
    const float* Wn = (const float*)d_in[6];
    const float* bn = (const float*)d_in[7];
    const float* Wo = (const float*)d_in[8];
    const float* bo = (const float*)d_in[9];
    const float* gamma = (const float*)d_in[10];

    char* wsb = (char*)d_ws;
    short* hsb = (short*)(wsb);                    // 0..8 MB  [4096,1024] bf16
    short* AOb = hsb;                              // aliases hsb (hsb dead after coords_mfma)
    short* Wvb = (short*)(wsb + (8 << 20));        // 8..10 MB
    short* Wob = (short*)(wsb + (10 << 20));       // 10..12 MB
    short* Vt  = (short*)(wsb + (12 << 20));       // 12..20 MB [b,h,dh,s] bf16 (half-swapped)
    short* ZA  = (short*)(wsb + (20 << 20));       // 20..24 MB [b,h,s,32] bf16
    short* ZB  = (short*)(wsb + (24 << 20));       // 24..28 MB [b,h,s,32] bf16
    short* Wnb = (short*)(wsb + (28 << 20));       // 28 MB + 32 KB [16,1024] bf16

    float* out_hidden = (float*)d_out;             // [B,S,D]
    float* out_coords = out_hidden + 4194304;      // [B,S,CD]

    f2bf_kernel<<<2048, 256, 0, stream>>>(hidden, hsb, 524288);
    f2bfW<<<1032, 256, 0, stream>>>(Wv, Wo, Wn, Wvb, Wob, Wnb);
    zker3<<<4096, 256, 0, stream>>>(coords, Wc, bc, gamma, ZA, ZB);
    gemm_mfma<0><<<dim3(16, 32), 256, 0, stream>>>(hsb, Wvb, bv, (void*)Vt);
    coords_mfma<<<256, 256, 0, stream>>>(hsb, Wnb, bn, out_coords);
    attn_mfma8<<<1024, 256, 0, stream>>>(ZA, ZB, Vt, AOb);
    gemm_mfma<1><<<dim3(16, 32), 256, 0, stream>>>(AOb, Wob, bo, (void*)out_hidden);
}